// Round 2
// baseline (383.947 us; speedup 1.0000x reference)
//
#include <hip/hip_runtime.h>

// ---------------------------------------------------------------------------
// SimpleBBoxHead on MI355X (gfx950)
// Key algebraic optimization: vision part of layer 1 has only B=16 unique
// rows -> contract [16 x 32768] @ W1[:32768] once (fp32, HBM-bound), then
// per-token layer-1 = V_contrib[batch_idx[t]] + grd_hidden @ W1[32768:] + b1.
// All big GEMMs in bf16 MFMA (threshold is bf16-level: 3.2e-2).
// ---------------------------------------------------------------------------

typedef __attribute__((ext_vector_type(8))) short bf16x8;
typedef __attribute__((ext_vector_type(4))) float f32x4;

#define LM_DIM 4096
#define V_DIM  1024
#define N_V    32
#define FF     1024
#define VIS_K  (V_DIM * N_V)     // 32768
#define NB     16
#define NTOK   2048

__device__ __forceinline__ unsigned short f2bf(float f) {
    unsigned int u = __float_as_uint(f);
    u += 0x7fffu + ((u >> 16) & 1u);   // round-to-nearest-even
    return (unsigned short)(u >> 16);
}
__device__ __forceinline__ float bf2f(unsigned short s) {
    return __uint_as_float(((unsigned int)s) << 16);
}

__device__ __forceinline__ void gload_lds16(const void* g, void* lds) {
    __builtin_amdgcn_global_load_lds(
        (const __attribute__((address_space(1))) unsigned int*)g,
        (__attribute__((address_space(3))) unsigned int*)lds,
        16, 0, 0);
}

// ---------------------------------------------------------------------------
// Zero the V_contrib accumulator (ws is poisoned 0xAA before every call)
// ---------------------------------------------------------------------------
__global__ void zero_vc(float* __restrict__ vc) {
    int i = blockIdx.x * blockDim.x + threadIdx.x;   // 16384 floats
    vc[i] = 0.f;
}

// ---------------------------------------------------------------------------
// V_contrib[b][n] = sum_k vis[b][k] * W1[k][n],  k < 32768  (fp32, split-K)
// grid 256 (k-slices of 128), block 1024 (one column each), atomicAdd out.
// Memory-bound: streams the 128 MB vision half of W1 exactly once.
// ---------------------------------------------------------------------------
__global__ __launch_bounds__(1024) void vis_contrib(
    const float* __restrict__ W1, const float* __restrict__ vis,
    float* __restrict__ vc)
{
    const int n  = threadIdx.x;          // 0..1023
    const int k0 = blockIdx.x * 128;
    __shared__ float sv[NB][128];
    for (int idx = threadIdx.x; idx < NB * 128; idx += 1024) {
        int b = idx >> 7, kk = idx & 127;
        sv[b][kk] = vis[(size_t)b * VIS_K + k0 + kk];
    }
    __syncthreads();
    float acc[NB];
#pragma unroll
    for (int b = 0; b < NB; ++b) acc[b] = 0.f;
    for (int kk = 0; kk < 128; ++kk) {
        float w = W1[(size_t)(k0 + kk) * FF + n];
#pragma unroll
        for (int b = 0; b < NB; ++b) acc[b] += sv[b][kk] * w;
    }
#pragma unroll
    for (int b = 0; b < NB; ++b) atomicAdd(&vc[b * FF + n], acc[b]);
}

// ---------------------------------------------------------------------------
// f32 -> bf16 elementwise, 8 elems/thread
// ---------------------------------------------------------------------------
__global__ void cvt_f32_bf16(const float* __restrict__ in,
                             unsigned short* __restrict__ out, int n8) {
    int i = blockIdx.x * blockDim.x + threadIdx.x;
    if (i >= n8) return;
    const float4* p = (const float4*)in + (size_t)i * 2;
    float4 a = p[0], b = p[1];
    union { unsigned short us[8]; uint4 v; } o;
    o.us[0] = f2bf(a.x); o.us[1] = f2bf(a.y); o.us[2] = f2bf(a.z); o.us[3] = f2bf(a.w);
    o.us[4] = f2bf(b.x); o.us[5] = f2bf(b.y); o.us[6] = f2bf(b.z); o.us[7] = f2bf(b.w);
    ((uint4*)out)[i] = o.v;
}

// ---------------------------------------------------------------------------
// Transpose + convert: dst[n][k] (bf16) = src[k][n] (f32).  64x64 LDS tiles.
// block (64,4), grid (K/64, N/64)
// ---------------------------------------------------------------------------
__global__ void tr_cvt(const float* __restrict__ src,
                       unsigned short* __restrict__ dst, int K, int N) {
    __shared__ float t[64][65];
    const int k0 = blockIdx.x * 64, n0 = blockIdx.y * 64;
    const int tx = threadIdx.x, ty = threadIdx.y;
    for (int r = ty; r < 64; r += 4)
        t[r][tx] = src[(size_t)(k0 + r) * N + n0 + tx];
    __syncthreads();
    for (int r = ty; r < 64; r += 4)
        dst[(size_t)(n0 + r) * K + k0 + tx] = f2bf(t[tx][r]);
}

// ---------------------------------------------------------------------------
// bf16 MFMA GEMM:  H[M][N] = f(A[M][K] @ BT[N][K]^T)
// 64x64 tile, BK=64, 256 threads = 4 waves (2x2), wave tile 32x32.
// global_load_lds(16B) with pre-swizzled global source (linear LDS dest),
// XOR-swizzled ds_read (byte ^= (row&7)<<4) -> conflict-free b128 reads.
// EPI==1: += Vc[tbi[row]][col] + bias, relu.  EPI==0: += bias, relu.
// ---------------------------------------------------------------------------
template <int EPI>
__global__ __launch_bounds__(256, 2) void gemm_bt(
    const unsigned short* __restrict__ A,   // [M][K] bf16
    const unsigned short* __restrict__ BT,  // [N][K] bf16
    const float* __restrict__ bias,         // [N]
    const float* __restrict__ Vc,           // [16][N] or null
    const int* __restrict__ tbi,            // [M] or null
    unsigned short* __restrict__ Hout,      // [M][N] bf16
    int M, int N, int K)
{
    __shared__ __align__(16) unsigned char smem[16384];
    unsigned char* sA = smem;          // [64 rows][64 k] bf16 = 8KB (swizzled)
    unsigned char* sB = smem + 8192;   // [64 cols][64 k] bf16 = 8KB (swizzled)

    const int tid  = threadIdx.x;
    const int lane = tid & 63;
    const int wv   = tid >> 6;        // 0..3
    const int wr   = wv >> 1;         // wave row 0..1  (32 rows each)
    const int wc   = wv & 1;          // wave col 0..1  (32 cols each)
    const int bm   = blockIdx.x * 64;
    const int bn   = blockIdx.y * 64;

    f32x4 acc[2][2];
#pragma unroll
    for (int m = 0; m < 2; ++m)
#pragma unroll
        for (int n = 0; n < 2; ++n) acc[m][n] = (f32x4){0.f, 0.f, 0.f, 0.f};

    for (int k0 = 0; k0 < K; k0 += 64) {
        __syncthreads();   // previous iteration's LDS reads complete
        // stage A and B tiles: 8 segments of 1KB each, per tile.
        // LDS dest linear (global_load_lds constraint, m104/m108);
        // global source pre-swizzled so the swizzled ds_read is correct (m173).
#pragma unroll
        for (int c = 0; c < 2; ++c) {
            int seg = wv * 2 + c;
            int p   = seg * 1024 + lane * 16;          // linear LDS byte
            int row = p >> 7;                          // 0..63
            int kb  = (p & 127) ^ ((row & 7) << 4);    // swizzled k-byte
            gload_lds16((const unsigned char*)A + ((size_t)(bm + row) * K + k0) * 2 + kb,
                        sA + seg * 1024);
        }
#pragma unroll
        for (int c = 0; c < 2; ++c) {
            int seg = wv * 2 + c;
            int p   = seg * 1024 + lane * 16;
            int row = p >> 7;
            int kb  = (p & 127) ^ ((row & 7) << 4);
            gload_lds16((const unsigned char*)BT + ((size_t)(bn + row) * K + k0) * 2 + kb,
                        sB + seg * 1024);
        }
        __syncthreads();   // drains vmcnt -> tiles visible

#pragma unroll
        for (int kk = 0; kk < 2; ++kk) {
            const int kbb = kk * 64 + (lane >> 4) * 16;  // this lane's 8 bf16 (bytes)
            bf16x8 av[2], bv[2];
#pragma unroll
            for (int m = 0; m < 2; ++m) {
                int r = wr * 32 + m * 16 + (lane & 15);
                av[m] = *(const bf16x8*)(sA + r * 128 + (kbb ^ ((r & 7) << 4)));
            }
#pragma unroll
            for (int n = 0; n < 2; ++n) {
                int r = wc * 32 + n * 16 + (lane & 15);
                bv[n] = *(const bf16x8*)(sB + r * 128 + (kbb ^ ((r & 7) << 4)));
            }
#pragma unroll
            for (int m = 0; m < 2; ++m)
#pragma unroll
                for (int n = 0; n < 2; ++n)
                    acc[m][n] = __builtin_amdgcn_mfma_f32_16x16x32_bf16(
                        av[m], bv[n], acc[m][n], 0, 0, 0);
        }
    }

    // Epilogue. C/D layout (m89-verified): col = lane&15, row = (lane>>4)*4+j
#pragma unroll
    for (int m = 0; m < 2; ++m) {
#pragma unroll
        for (int j = 0; j < 4; ++j) {
            int grow = bm + wr * 32 + m * 16 + (lane >> 4) * 4 + j;
            const float* vrow = (EPI == 1) ? (Vc + (size_t)tbi[grow] * N) : nullptr;
#pragma unroll
            for (int n = 0; n < 2; ++n) {
                int gcol = bn + wc * 32 + n * 16 + (lane & 15);
                float v = acc[m][n][j] + bias[gcol];
                if (EPI == 1) v += vrow[gcol];
                v = fmaxf(v, 0.f);
                Hout[(size_t)grow * N + gcol] = f2bf(v);
            }
        }
    }
}

// ---------------------------------------------------------------------------
// Final projection: out[t][j] = sum_k h[t][k]*W5[k][j] + b5[j]   (N=6, fp32)
// one wave per token, shuffle reduction
// ---------------------------------------------------------------------------
__global__ __launch_bounds__(256) void final_proj(
    const unsigned short* __restrict__ H, const float* __restrict__ W5,
    const float* __restrict__ b5, float* __restrict__ out)
{
    const int t    = blockIdx.x * 4 + (threadIdx.x >> 6);
    const int lane = threadIdx.x & 63;
    float s[6] = {0.f, 0.f, 0.f, 0.f, 0.f, 0.f};
#pragma unroll
    for (int i = 0; i < 16; ++i) {
        int k = i * 64 + lane;
        float h = bf2f(H[(size_t)t * FF + k]);
#pragma unroll
        for (int j = 0; j < 6; ++j) s[j] += h * W5[(size_t)k * 6 + j];
    }
#pragma unroll
    for (int j = 0; j < 6; ++j) {
#pragma unroll
        for (int off = 32; off > 0; off >>= 1) s[j] += __shfl_down(s[j], off);
    }
    if (lane == 0) {
#pragma unroll
        for (int j = 0; j < 6; ++j) out[(size_t)t * 6 + j] = s[j] + b5[j];
    }
}

// ---------------------------------------------------------------------------
extern "C" void kernel_launch(void* const* d_in, const int* in_sizes, int n_in,
                              void* d_out, int out_size, void* d_ws, size_t ws_size,
                              hipStream_t stream) {
    const float* grd = (const float*)d_in[0];
    const float* vis = (const float*)d_in[1];
    const int*   tbi = (const int*)d_in[2];
    const float* W1  = (const float*)d_in[3];
    const float* b1  = (const float*)d_in[4];
    const float* W2  = (const float*)d_in[5];
    const float* b2  = (const float*)d_in[6];
    const float* W3  = (const float*)d_in[7];
    const float* b3  = (const float*)d_in[8];
    const float* W4  = (const float*)d_in[9];
    const float* b4  = (const float*)d_in[10];
    const float* W5  = (const float*)d_in[11];
    const float* b5  = (const float*)d_in[12];
    float* out = (float*)d_out;

    char* ws = (char*)d_ws;
    // workspace layout (~40 MB total)
    float*          Vc    = (float*)ws;                                  //  64 KB
    unsigned short* grdb  = (unsigned short*)(ws + (1u << 16));          //  16 MB
    unsigned short* W1lT  = (unsigned short*)(ws + 16842752);            //   8 MB
    unsigned short* W2T   = (unsigned short*)(ws + 25231360);            //   2 MB
    unsigned short* W3T   = (unsigned short*)(ws + 27328512);            //   2 MB
    unsigned short* W4T   = (unsigned short*)(ws + 29425664);            //   2 MB
    unsigned short* hA    = (unsigned short*)(ws + 31522816);            //   4 MB
    unsigned short* hB    = (unsigned short*)(ws + 35717120);            //   4 MB

    zero_vc<<<16, 1024, 0, stream>>>(Vc);
    vis_contrib<<<256, 1024, 0, stream>>>(W1, vis, Vc);

    cvt_f32_bf16<<<4096, 256, 0, stream>>>(grd, grdb, NTOK * LM_DIM / 8);
    tr_cvt<<<dim3(LM_DIM / 64, FF / 64), dim3(64, 4), 0, stream>>>(
        W1 + (size_t)VIS_K * FF, W1lT, LM_DIM, FF);
    tr_cvt<<<dim3(FF / 64, FF / 64), dim3(64, 4), 0, stream>>>(W2, W2T, FF, FF);
    tr_cvt<<<dim3(FF / 64, FF / 64), dim3(64, 4), 0, stream>>>(W3, W3T, FF, FF);
    tr_cvt<<<dim3(FF / 64, FF / 64), dim3(64, 4), 0, stream>>>(W4, W4T, FF, FF);

    // layer 1 (language half) + vision contrib + bias + relu
    gemm_bt<1><<<dim3(NTOK / 64, FF / 64), 256, 0, stream>>>(
        grdb, W1lT, b1, Vc, tbi, hA, NTOK, FF, LM_DIM);
    // layers 2..4
    gemm_bt<0><<<dim3(NTOK / 64, FF / 64), 256, 0, stream>>>(
        hA, W2T, b2, nullptr, nullptr, hB, NTOK, FF, FF);
    gemm_bt<0><<<dim3(NTOK / 64, FF / 64), 256, 0, stream>>>(
        hB, W3T, b3, nullptr, nullptr, hA, NTOK, FF, FF);
    gemm_bt<0><<<dim3(NTOK / 64, FF / 64), 256, 0, stream>>>(
        hA, W4T, b4, nullptr, nullptr, hB, NTOK, FF, FF);
    // layer 5
    final_proj<<<NTOK / 4, 256, 0, stream>>>(hB, W5, b5, out);
}

// Round 3
// 356.605 us; speedup vs baseline: 1.0767x; 1.0767x over previous
//
#include <hip/hip_runtime.h>

// ---------------------------------------------------------------------------
// SimpleBBoxHead on MI355X (gfx950) — round 3
// - vision half of layer 1 factorized to [16 x 32768] @ W1_vis (fp32, HBM-
//   bound), per-token gather folded into GEMM-1 epilogue.
// - vis contraction: 2-stage partials (no 4M-atomic contention).
// - GEMMs: bf16 MFMA, 64x64 tile, 2-phase double-buffered LDS (T3-minimum),
//   XCD-swizzled grid.
// - prep (f32->bf16 cvt + 4 weight transposes) fused into one kernel.
// ---------------------------------------------------------------------------

typedef __attribute__((ext_vector_type(8))) short bf16x8;
typedef __attribute__((ext_vector_type(4))) float f32x4;

#define LM_DIM 4096
#define FF     1024
#define VIS_K  32768
#define NB     16
#define NTOK   2048

__device__ __forceinline__ unsigned short f2bf(float f) {
    unsigned int u = __float_as_uint(f);
    u += 0x7fffu + ((u >> 16) & 1u);   // round-to-nearest-even
    return (unsigned short)(u >> 16);
}
__device__ __forceinline__ float bf2f(unsigned short s) {
    return __uint_as_float(((unsigned int)s) << 16);
}

__device__ __forceinline__ void gload_lds16(const void* g, void* lds) {
    __builtin_amdgcn_global_load_lds(
        (const __attribute__((address_space(1))) unsigned int*)g,
        (__attribute__((address_space(3))) unsigned int*)lds,
        16, 0, 0);
}

// ---------------------------------------------------------------------------
// Stage 1: pb[ks][b][n] = sum_{kk<128} vis[b][ks*128+kk] * W1[ks*128+kk][n]
// 256 blocks (one k-slice each) x 1024 threads (one column each).
// Exclusive writes -> no atomics, no zeroing.
// ---------------------------------------------------------------------------
__global__ __launch_bounds__(1024) void vis_partial(
    const float* __restrict__ W1, const float* __restrict__ vis,
    float* __restrict__ pb)
{
    const int n  = threadIdx.x;
    const int ks = blockIdx.x;
    const int k0 = ks * 128;
    __shared__ float sv[NB][128];
    for (int idx = threadIdx.x; idx < NB * 128; idx += 1024) {
        int b = idx >> 7, kk = idx & 127;
        sv[b][kk] = vis[(size_t)b * VIS_K + k0 + kk];
    }
    __syncthreads();
    float acc[NB];
#pragma unroll
    for (int b = 0; b < NB; ++b) acc[b] = 0.f;
    for (int kk = 0; kk < 128; ++kk) {
        float w = W1[(size_t)(k0 + kk) * FF + n];
#pragma unroll
        for (int b = 0; b < NB; ++b) acc[b] += sv[b][kk] * w;
    }
#pragma unroll
    for (int b = 0; b < NB; ++b)
        pb[((size_t)ks * NB + b) * FF + n] = acc[b];
}

// ---------------------------------------------------------------------------
// Stage 2: Vc[b][n] = sum_ks pb[ks][b][n].  65536 threads; each sums a
// quarter (64 slices) and atomically adds (4 contenders/address; Vc
// pre-zeroed via hipMemsetAsync). Fully coalesced 256B/wave reads.
// ---------------------------------------------------------------------------
__global__ __launch_bounds__(256) void vis_reduce(
    const float* __restrict__ pb, float* __restrict__ vc)
{
    const int lin = blockIdx.x * 256 + threadIdx.x;   // 0..65535
    const int n = lin & 1023;
    const int r = lin >> 10;                          // 0..63
    const int b = r >> 2;
    const int q = r & 3;
    float s = 0.f;
#pragma unroll 4
    for (int i = 0; i < 64; ++i) {
        int ks = q * 64 + i;
        s += pb[((size_t)ks * NB + b) * FF + n];
    }
    atomicAdd(&vc[b * FF + n], s);
}

// ---------------------------------------------------------------------------
// Fused prep: grd f32->bf16 cvt (blocks 0..4095) + 4 weight transposes
// (dst[n][k] bf16 = src[k][n] f32).  Block (64,4).
// ---------------------------------------------------------------------------
__global__ __launch_bounds__(256) void prep_all(
    const float* __restrict__ grd, unsigned short* __restrict__ grdb,
    const float* __restrict__ W1l, unsigned short* __restrict__ W1lT,
    const float* __restrict__ W2,  unsigned short* __restrict__ W2T,
    const float* __restrict__ W3,  unsigned short* __restrict__ W3T,
    const float* __restrict__ W4,  unsigned short* __restrict__ W4T)
{
    __shared__ float t[64][65];
    const int bid = blockIdx.x;
    const int tx = threadIdx.x, ty = threadIdx.y;

    if (bid < 4096) {            // grd cvt: 8 elems/thread, 1M threads total
        int i = bid * 256 + ty * 64 + tx;
        const float4* p = (const float4*)grd + (size_t)i * 2;
        float4 a = p[0], bvec = p[1];
        union { unsigned short us[8]; uint4 v; } o;
        o.us[0] = f2bf(a.x); o.us[1] = f2bf(a.y);
        o.us[2] = f2bf(a.z); o.us[3] = f2bf(a.w);
        o.us[4] = f2bf(bvec.x); o.us[5] = f2bf(bvec.y);
        o.us[6] = f2bf(bvec.z); o.us[7] = f2bf(bvec.w);
        ((uint4*)grdb)[i] = o.v;
        return;
    }
    const float* src; unsigned short* dst; int K, tt;
    if (bid < 5120)      { src = W1l; dst = W1lT; K = LM_DIM; tt = bid - 4096; }
    else if (bid < 5376) { src = W2;  dst = W2T;  K = FF;     tt = bid - 5120; }
    else if (bid < 5632) { src = W3;  dst = W3T;  K = FF;     tt = bid - 5376; }
    else                 { src = W4;  dst = W4T;  K = FF;     tt = bid - 5632; }
    const int tilesx = K / 64;                  // tiles along K
    const int k0 = (tt % tilesx) * 64, n0 = (tt / tilesx) * 64;
    for (int r = ty; r < 64; r += 4)
        t[r][tx] = src[(size_t)(k0 + r) * FF + n0 + tx];
    __syncthreads();
    for (int r = ty; r < 64; r += 4)
        dst[(size_t)(n0 + r) * K + k0 + tx] = f2bf(t[tx][r]);
}

// ---------------------------------------------------------------------------
// bf16 MFMA GEMM:  H[M][N] = relu(A[M][K] @ BT[N][K]^T + bias [+ Vc gather])
// 64x64 tile, BK=64, 4 waves (2x2, 32x32 each), 2-phase double-buffered LDS:
// issue next tile's global_load_lds BEFORE current tile's ds_read+MFMA, one
// barrier per K-step (T3-minimum).  LDS dest linear (m104), global source
// pre-swizzled (m173), XOR-swizzled ds_read (byte ^= (row&7)<<4).
// XCD-aware block swizzle (nwg=512, %8==0 -> bijective).
// ---------------------------------------------------------------------------
template <int EPI>
__global__ __launch_bounds__(256, 2) void gemm_bt(
    const unsigned short* __restrict__ A,   // [M][K] bf16
    const unsigned short* __restrict__ BT,  // [N][K] bf16
    const float* __restrict__ bias,         // [N]
    const float* __restrict__ Vc,           // [16][N] or null
    const int* __restrict__ tbi,            // [M] or null
    unsigned short* __restrict__ Hout,      // [M][N] bf16
    int M, int N, int K)
{
    __shared__ __align__(16) unsigned char smem[32768];  // 2 x (8KB A + 8KB B)

    const int tid  = threadIdx.x;
    const int lane = tid & 63;
    const int wv   = tid >> 6;
    const int wr   = wv >> 1;
    const int wc   = wv & 1;

    // XCD swizzle: consecutive new-ids land on the same XCD -> L2 panel reuse
    const int nwg  = gridDim.x * gridDim.y;          // 512
    const int bid0 = blockIdx.y * gridDim.x + blockIdx.x;
    const int cpx  = nwg >> 3;
    const int bid  = (bid0 & 7) * cpx + (bid0 >> 3);
    const int bm   = (bid % gridDim.x) * 64;
    const int bn   = (bid / gridDim.x) * 64;

    // staging: 8 x 1KB segments per tile; this thread's segment/offset
    const int seg  = wv * 2;                          // c in {0,1} adds 1
    f32x4 acc[2][2];
#pragma unroll
    for (int m = 0; m < 2; ++m)
#pragma unroll
        for (int n = 0; n < 2; ++n) acc[m][n] = (f32x4){0.f, 0.f, 0.f, 0.f};

    auto stage = [&](int p, int k0) {
        unsigned char* sA = smem + p * 16384;
        unsigned char* sB = sA + 8192;
#pragma unroll
        for (int c = 0; c < 2; ++c) {
            int sg  = seg + c;
            int off = sg * 1024 + lane * 16;          // linear LDS byte
            int row = off >> 7;                       // 0..63
            int kb  = (off & 127) ^ ((row & 7) << 4); // pre-swizzled source
            gload_lds16((const unsigned char*)A  + ((size_t)(bm + row) * K + k0) * 2 + kb,
                        sA + sg * 1024);
            gload_lds16((const unsigned char*)BT + ((size_t)(bn + row) * K + k0) * 2 + kb,
                        sB + sg * 1024);
        }
    };
    auto compute = [&](int p) {
        const unsigned char* sA = smem + p * 16384;
        const unsigned char* sB = sA + 8192;
#pragma unroll
        for (int kk = 0; kk < 2; ++kk) {
            const int kbb = kk * 64 + (lane >> 4) * 16;
            bf16x8 av[2], bv[2];
#pragma unroll
            for (int m = 0; m < 2; ++m) {
                int r = wr * 32 + m * 16 + (lane & 15);
                av[m] = *(const bf16x8*)(sA + r * 128 + (kbb ^ ((r & 7) << 4)));
            }
#pragma unroll
            for (int n = 0; n < 2; ++n) {
                int r = wc * 32 + n * 16 + (lane & 15);
                bv[n] = *(const bf16x8*)(sB + r * 128 + (kbb ^ ((r & 7) << 4)));
            }
#pragma unroll
            for (int m = 0; m < 2; ++m)
#pragma unroll
                for (int n = 0; n < 2; ++n)
                    acc[m][n] = __builtin_amdgcn_mfma_f32_16x16x32_bf16(
                        av[m], bv[n], acc[m][n], 0, 0, 0);
        }
    };

    const int nt = K >> 6;
    stage(0, 0);
    __syncthreads();                       // vmcnt(0) drain + barrier
    for (int t = 0; t < nt; ++t) {
        if (t + 1 < nt) stage((t + 1) & 1, (t + 1) << 6);  // prefetch in flight
        compute(t & 1);                                     // overlaps loads
        __syncthreads();                   // drains lgkm + vmcnt, one/iter
    }

    // Epilogue. C/D layout (m89): col = lane&15, row = (lane>>4)*4+j
#pragma unroll
    for (int m = 0; m < 2; ++m) {
#pragma unroll
        for (int j = 0; j < 4; ++j) {
            int grow = bm + wr * 32 + m * 16 + (lane >> 4) * 4 + j;
            const float* vrow = (EPI == 1) ? (Vc + (size_t)tbi[grow] * N) : nullptr;
#pragma unroll
            for (int n = 0; n < 2; ++n) {
                int gcol = bn + wc * 32 + n * 16 + (lane & 15);
                float v = acc[m][n][j] + bias[gcol];
                if (EPI == 1) v += vrow[gcol];
                v = fmaxf(v, 0.f);
                Hout[(size_t)grow * N + gcol] = f2bf(v);
            }
        }
    }
}

// ---------------------------------------------------------------------------
// Final projection: out[t][j] = sum_k h[t][k]*W5[k][j] + b5[j]   (N=6, fp32)
// ---------------------------------------------------------------------------
__global__ __launch_bounds__(256) void final_proj(
    const unsigned short* __restrict__ H, const float* __restrict__ W5,
    const float* __restrict__ b5, float* __restrict__ out)
{
    const int t    = blockIdx.x * 4 + (threadIdx.x >> 6);
    const int lane = threadIdx.x & 63;
    float s[6] = {0.f, 0.f, 0.f, 0.f, 0.f, 0.f};
#pragma unroll
    for (int i = 0; i < 16; ++i) {
        int k = i * 64 + lane;
        float h = bf2f(H[(size_t)t * FF + k]);
#pragma unroll
        for (int j = 0; j < 6; ++j) s[j] += h * W5[(size_t)k * 6 + j];
    }
#pragma unroll
    for (int j = 0; j < 6; ++j) {
#pragma unroll
        for (int off = 32; off > 0; off >>= 1) s[j] += __shfl_down(s[j], off);
    }
    if (lane == 0) {
#pragma unroll
        for (int j = 0; j < 6; ++j) out[(size_t)t * 6 + j] = s[j] + b5[j];
    }
}

// ---------------------------------------------------------------------------
extern "C" void kernel_launch(void* const* d_in, const int* in_sizes, int n_in,
                              void* d_out, int out_size, void* d_ws, size_t ws_size,
                              hipStream_t stream) {
    const float* grd = (const float*)d_in[0];
    const float* vis = (const float*)d_in[1];
    const int*   tbi = (const int*)d_in[2];
    const float* W1  = (const float*)d_in[3];
    const float* b1  = (const float*)d_in[4];
    const float* W2  = (const float*)d_in[5];
    const float* b2  = (const float*)d_in[6];
    const float* W3  = (const float*)d_in[7];
    const float* b3  = (const float*)d_in[8];
    const float* W4  = (const float*)d_in[9];
    const float* b4  = (const float*)d_in[10];
    const float* W5  = (const float*)d_in[11];
    const float* b5  = (const float*)d_in[12];
    float* out = (float*)d_out;

    char* ws = (char*)d_ws;
    float*          pb    = (float*)ws;                           // 16 MB
    float*          Vc    = (float*)(ws + 16777216);              // 64 KB
    unsigned short* grdb  = (unsigned short*)(ws + 16842752);     // 16 MB
    unsigned short* W1lT  = (unsigned short*)(ws + 33619968);     //  8 MB
    unsigned short* W2T   = (unsigned short*)(ws + 42008576);     //  2 MB
    unsigned short* W3T   = (unsigned short*)(ws + 44105728);     //  2 MB
    unsigned short* W4T   = (unsigned short*)(ws + 46202880);     //  2 MB
    unsigned short* hA    = (unsigned short*)(ws + 48300032);     //  4 MB
    unsigned short* hB    = (unsigned short*)(ws + 52494336);     //  4 MB

    hipMemsetAsync(Vc, 0, NB * FF * sizeof(float), stream);
    vis_partial<<<256, 1024, 0, stream>>>(W1, vis, pb);
    vis_reduce<<<256, 256, 0, stream>>>(pb, Vc);

    prep_all<<<5888, dim3(64, 4), 0, stream>>>(
        grd, grdb, W1 + (size_t)VIS_K * FF, W1lT, W2, W2T, W3, W3T, W4, W4T);

    gemm_bt<1><<<dim3(NTOK / 64, FF / 64), 256, 0, stream>>>(
        grdb, W1lT, b1, Vc, tbi, hA, NTOK, FF, LM_DIM);
    gemm_bt<0><<<dim3(NTOK / 64, FF / 64), 256, 0, stream>>>(
        hA, W2T, b2, nullptr, nullptr, hB, NTOK, FF, FF);
    gemm_bt<0><<<dim3(NTOK / 64, FF / 64), 256, 0, stream>>>(
        hB, W3T, b3, nullptr, nullptr, hA, NTOK, FF, FF);
    gemm_bt<0><<<dim3(NTOK / 64, FF / 64), 256, 0, stream>>>(
        hA, W4T, b4, nullptr, nullptr, hB, NTOK, FF, FF);

    final_proj<<<NTOK / 4, 256, 0, stream>>>(hB, W5, b5, out);
}